// Round 6
// baseline (147.112 us; speedup 1.0000x reference)
//
#include <hip/hip_runtime.h>
#include <math.h>

#define N     4096
#define NIMG  2048
#define TX    56          // output tile width
#define TY    32          // output tile height
#define DW    64          // D-region width  = TX + 8 (1 lane per column)
#define DH    40          // D-region height = TY + 8
#define IPP   25          // img patch pitch (odd -> conflict-free)
#define STP   41          // ST pitch over rows (odd; 4*41 mod 32 = 4 -> 2-way on quad writes, free)
#define VP    65          // V pitch (== 1 mod 32, conflict-free in stages 2/3)
#define T2P   57          // transpose buffer pitch (per-wave use: worst 2-way, free)
#define GBX   74          // grid blocks in x
#define GBY   128         // grid blocks in y

// Gaussian kernel sigma=1, r=4 (double-precision eval of reference formula)
#define KW0 0.00013383063f
#define KW1 0.00443186160f
#define KW2 0.05399112800f
#define KW3 0.24197144000f
#define KW4 0.39894346870f

__device__ __forceinline__ int symi(int g) {
    g = (g < 0) ? (-1 - g) : g;
    g = (g >= N) ? (2 * N - 1 - g) : g;
    return g;
}

__global__ __launch_bounds__(256, 4)
void TensorAugment_79216376807666_kernel(const float* __restrict__ img,
                                         const float* __restrict__ noise,
                                         float* __restrict__ out) {
    __shared__ float ST[DW * STP];     // D tile col-major [c][row]                 (10.5 KB)
    __shared__ float UN[TY * VP];      // union: IP (stages 0-1) / V (stages 2-3)   (8.3 KB)
    __shared__ float T2[TY * T2P];     // per-wave transpose buffer                 (7.3 KB)
    float* const IP = UN;
    float* const V  = UN;

    const int tid  = threadIdx.x;
    const int lane = tid & 63;
    const int wave = tid >> 6;

    // ---- XCD-aware swizzle: each XCD (b&7) owns a contiguous 74x16 slab ----
    int b   = blockIdx.y * GBX + blockIdx.x;
    int xcd = b & 7;
    int i   = b >> 3;                   // 0..1183
    int bx  = i % GBX;                  // 0..73
    int by  = xcd * 16 + i / GBX;       // 0..127

    const int x0 = bx * TX;
    const int y0 = by * TY;
    const bool interior = (bx >= 1) && (bx <= 72) && (by >= 1) && (by <= 126);

    const float kk[9] = {KW0, KW1, KW2, KW3, KW4, KW3, KW2, KW1, KW0};

    // ---- interior: prefetch noise (overlaps img staging + barrier) ----
    const int g  = lane & 15;
    const int rr = lane >> 4;
    const int rowbase = wave * 4 + rr;           // 0..15
    float4 nv0, nv1, nv2;
    if (interior) {
        const float* npz = noise + (size_t)(y0 - 4) * N + (x0 - 4) + 4 * g;
        nv0 = *reinterpret_cast<const float4*>(npz + (size_t)rowbase * N);
        nv1 = *reinterpret_cast<const float4*>(npz + (size_t)(rowbase + 16) * N);
        if (rowbase + 32 < DH)
            nv2 = *reinterpret_cast<const float4*>(npz + (size_t)(rowbase + 32) * N);
    }

    // ---- block-uniform staged img ranges (generic; exact for interior) ----
    int gxa = x0 - 4, gxb = x0 + DW - 5;
    int mxa = symi(gxa), mxb = symi(gxb);
    int gxmin = min(mxa, mxb), gxmax = max(mxa, mxb);
    if (gxa <= 0) gxmin = 0;
    if (gxb >= N - 1) gxmax = N - 1;
    int umin = (N - 1) - gxmax, umax = (N - 1) - gxmin;
    int r0min = (umin - 1) >> 1;
    int r0max = (umax - 1) >> 1;
    int nrows = r0max - r0min + 2;       // <= 34

    int gya = y0 - 4, gyb = y0 + DH - 5;
    int mya = symi(gya), myb = symi(gyb);
    int gymin = min(mya, myb), gymax = max(mya, myb);
    if (gya <= 0) gymin = 0;
    if (gyb >= N - 1) gymax = N - 1;
    int c0min = (gymin - 1) >> 1;
    int c0max = (gymax - 1) >> 1;
    int ncols = c0max - c0min + 2;       // <= 24

    // ---- stage 0: img patch -> IP (coalesced) ----
    {
        int c = tid & 31;
        int r = tid >> 5;
        if (interior) {
            const float* ipb = img + (size_t)r0min * NIMG + c0min;
            for (; r < nrows; r += 8)
                if (c < ncols) IP[r * IPP + c] = ipb[r * NIMG + c];
        } else {
            for (; r < nrows; r += 8) {
                if (c < ncols) {
                    int ir = min(max(r0min + r, 0), NIMG - 1);
                    int ic = min(max(c0min + c, 0), NIMG - 1);
                    IP[r * IPP + c] = img[ir * NIMG + ic];
                }
            }
        }
    }
    __syncthreads();

    // ---- stage 1: D = bilinear(rot) + 0.01*noise, column-major into ST ----
    if (interior) {
        // lane g handles D cols 4g..4g+3 of one D row; quad rr picks the row.
        int sbase = (30 - 2 * g) * IPP;           // staged img row (m-2)
        float4 nvv[3] = {nv0, nv1, nv2};
#pragma unroll
        for (int it = 0; it < 3; ++it) {
            int row = it * 16 + rowbase;          // 0..47; skip >=40
            if (row < DH) {
                int jc  = (row + 1) >> 1;
                float wc1 = (row & 1) ? 0.25f : 0.75f;
                float wc0 = 1.0f - wc1;
                float4 nv = nvv[it];
                int bofs = sbase + jc;
                float t0 = fmaf(wc0, IP[bofs],           wc1 * IP[bofs + 1]);            // m-2
                float t1 = fmaf(wc0, IP[bofs + IPP],     wc1 * IP[bofs + IPP + 1]);      // m-1
                float t2 = fmaf(wc0, IP[bofs + 2 * IPP], wc1 * IP[bofs + 2 * IPP + 1]);  // m
                float t3 = fmaf(wc0, IP[bofs + 3 * IPP], wc1 * IP[bofs + 3 * IPP + 1]);  // m+1
                float D0 = fmaf(0.75f, t2, 0.25f * t3);
                float D1 = fmaf(0.25f, t1, 0.75f * t2);
                float D2 = fmaf(0.75f, t1, 0.25f * t2);
                float D3 = fmaf(0.25f, t0, 0.75f * t1);
                int sb = (4 * g) * STP + row;
                ST[sb]           = fmaf(0.01f, nv.x, D0);
                ST[sb + STP]     = fmaf(0.01f, nv.y, D1);
                ST[sb + 2 * STP] = fmaf(0.01f, nv.z, D2);
                ST[sb + 3 * STP] = fmaf(0.01f, nv.w, D3);
            }
        }
    } else {
        // generic edge path (scalar, symmetric mapping)
        int c   = lane;
        int gxm = symi(x0 - 4 + c);
        int u   = (N - 1) - gxm;
        int r0  = (u - 1) >> 1;
        float wr1 = (u & 1) ? 0.25f : 0.75f;
        float wr0 = 1.0f - wr1;
        int a0 = (r0 - r0min) * IPP;
#pragma unroll
        for (int k = 0; k < 10; ++k) {
            int row = wave + 4 * k;               // 0..39
            int gym = symi(y0 - 4 + row);
            int c0  = (gym - 1) >> 1;
            float wc1 = (gym & 1) ? 0.25f : 0.75f;
            float wc0 = 1.0f - wc1;
            int jc = c0 - c0min;
            float nvs = noise[(size_t)gym * N + gxm];
            float f0 = IP[a0 + jc],       f1 = IP[a0 + jc + 1];
            float f2 = IP[a0 + IPP + jc], f3 = IP[a0 + IPP + jc + 1];
            float top = fmaf(wc0, f0, wc1 * f1);
            float bot = fmaf(wc0, f2, wc1 * f3);
            ST[c * STP + row] = fmaf(wr0, top, wr1 * bot) + 0.01f * nvs;
        }
    }
    __syncthreads();   // last block-wide barrier: ST ready, IP dead

    // From here on, all data flow is WAVE-PRIVATE (wave w owns output rows
    // 8w..8w+7): no __syncthreads needed; lgkmcnt ordering suffices.

    // ---- stage 2: vertical blur, sliding window (8 outputs/thread) ----
    {
        int c  = lane;
        int rb = wave * 8;                        // 0,8,16,24
        float win[16];
        int ab = c * STP + rb;
#pragma unroll
        for (int k = 0; k < 16; ++k) win[k] = ST[ab + k];   // contiguous -> ds_read2
#pragma unroll
        for (int j = 0; j < 8; ++j) {
            float acc = 0.0f;
#pragma unroll
            for (int i2 = 0; i2 < 9; ++i2) acc = fmaf(kk[i2], win[j + i2], acc);
            V[(rb + j) * VP + c] = acc;
        }
    }

    // ---- stage 3: horizontal blur + relu + log1p -> per-wave transpose ----
    {
        int r = tid >> 3;                         // 8*wave + (lane>>3): wave-private rows
        int s = tid & 7;                          // 0..7 (7 cols each)
        float w2[15];
        int vb = r * VP + s * 7;
#pragma unroll
        for (int k = 0; k < 15; ++k) w2[k] = V[vb + k];     // contiguous -> ds_read2
#pragma unroll
        for (int j = 0; j < 7; ++j) {
            float acc = 0.0f;
#pragma unroll
            for (int i2 = 0; i2 < 9; ++i2) acc = fmaf(kk[i2], w2[j + i2], acc);
            acc = fmaxf(acc, 0.0f);
            T2[r * T2P + s * 7 + j] = __logf(1.0f + acc);
        }
    }

    // ---- stage 4: coalesced store of this wave's 8 rows ----
    {
        int gx = x0 + lane;
        if (lane < TX && gx < N) {
#pragma unroll
            for (int q = 0; q < 8; ++q) {
                int r = wave * 8 + q;
                out[(size_t)(y0 + r) * N + gx] = T2[r * T2P + lane];
            }
        }
    }
}

extern "C" void kernel_launch(void* const* d_in, const int* in_sizes, int n_in,
                              void* d_out, int out_size, void* d_ws, size_t ws_size,
                              hipStream_t stream) {
    const float* img   = (const float*)d_in[0];   // (1, 2048, 2048) f32
    const float* noise = (const float*)d_in[1];   // (1, 4096, 4096) f32
    float* out = (float*)d_out;                   // (1, 4096, 4096) f32

    dim3 grid(GBX, GBY);                          // 74 x 128 blocks (swizzled in-kernel)
    TensorAugment_79216376807666_kernel<<<grid, 256, 0, stream>>>(img, noise, out);
}